// Round 8
// baseline (456.151 us; speedup 1.0000x reference)
//
#include <hip/hip_runtime.h>
#include <hip/hip_bf16.h>

#define H 160
#define W 160
#define HW 25600
#define ROWB 40960      // W * 256 bytes per NHWC row

typedef __attribute__((ext_vector_type(8))) short bf16x8;
typedef __attribute__((ext_vector_type(4))) float f32x4;
typedef __attribute__((ext_vector_type(8))) unsigned short ushort8v;
typedef __attribute__((ext_vector_type(4))) unsigned short ushort4v;

typedef __attribute__((address_space(1))) const unsigned int gu32;
typedef __attribute__((address_space(3))) unsigned int lu32;

__device__ __forceinline__ void gload16(const void* g, void* l) {
    __builtin_amdgcn_global_load_lds((gu32*)g, (lu32*)l, 16, 0, 0);
}

__device__ __forceinline__ unsigned short f2b(float f) {
    unsigned int u = __float_as_uint(f);
    unsigned int r = (u + 0x7fffu + ((u >> 16) & 1u)) >> 16;
    return (unsigned short)r;
}
__device__ __forceinline__ float b2f(unsigned short b) {
    return __uint_as_float(((unsigned int)b) << 16);
}

#define LGKM0() asm volatile("s_waitcnt lgkmcnt(0)" ::: "memory")
#define BARRIER() asm volatile("s_barrier" ::: "memory")

// ---------------------------------------------------------------------------
// d_out scratch layout (10,240,000 B; dead until head_kernel rewrites it):
//   [0, 6553600)        act X  (swizzled NHWC bf16)
//   [6553600, 7733248)  wbf: 4 layers x 36 planes x 8192 B ([tap][kk][co][64B])
//   [7733248, 7737344)  invshift: 4 layers x (inv[128], shift[128]) f32
// ws layout (7,440,400 B — proven budget):
//   [0, 6553600)        act Y
//   [6553600, 7372800)  mf (8 x 25600 f32)
//   [7372800, 7440400)  params (100 x 169 f32)
// ---------------------------------------------------------------------------

// ===========================================================================
// prep_weights v2 (coalesced): thread = (l,co,ci) -> 65,536 threads = 256
// blocks EXACT (bug in R7 was 576 blocks -> OOB tw reads -> GPU fault).
// Reads 9 contiguous fp32, writes 9 bf16 into planes [l][tap][kk][co][32ci].
// ===========================================================================
__global__ __launch_bounds__(256) void prep_weights(
    const float* __restrict__ tw,
    const float* __restrict__ gamma, const float* __restrict__ beta,
    const float* __restrict__ mean,  const float* __restrict__ var,
    char* __restrict__ wbf, float* __restrict__ invshift)
{
    int idx = blockIdx.x * 256 + threadIdx.x;     // 65,536 exact (256 blocks)
    int ci = idx & 127;
    int co = (idx >> 7) & 127;
    int l  = idx >> 14;                            // 0..3
    int kk = ci >> 5;
    int cw = ci & 31;
    const float* src = tw + ((l * 128 + co) * 128 + ci) * 9;
    char* dst = wbf + l * 294912 + kk * 8192 + co * 64 + cw * 2;
#pragma unroll
    for (int t = 0; t < 9; ++t)
        *(unsigned short*)(dst + t * 32768) = f2b(src[t]);

    if (blockIdx.x == 0) {
        for (int c = threadIdx.x; c < 512; c += 256) {
            int ll = c >> 7, ch = c & 127;
            float inv = gamma[ll * 128 + ch] * rsqrtf(var[ll * 128 + ch] + 1e-5f);
            float sh  = beta[ll * 128 + ch] - mean[ll * 128 + ch] * inv;
            invshift[ll * 256 + ch] = inv;
            invshift[ll * 256 + 128 + ch] = sh;
        }
    }
}

// ===========================================================================
// prep_input: cnn batch0 fp32 NCHW -> swizzled NHWC bf16 (act X)
// ===========================================================================
__global__ __launch_bounds__(256) void prep_input(
    const float* __restrict__ cnn, char* __restrict__ actX)
{
    int idx = blockIdx.x * 256 + threadIdx.x;   // 409,600 exact
    int cb = idx & 15;
    int p  = idx >> 4;
    int x  = p % W;
    int key = (x & 7) << 5;
    int ci0 = cb * 8;
    ushort8v o;
#pragma unroll
    for (int j = 0; j < 8; ++j)
        o[j] = f2b(cnn[(ci0 + j) * HW + p]);
    *(ushort8v*)(actX + p * 256 + ((cb * 16) ^ key)) = o;
}

// ===========================================================================
// conv_mfma v3: 3x3 SAME conv 128->128 (+BN+ReLU).
// Block 256 thr / 4 waves, tile 128co x 64px (16w x 4h). Grid (10,40) = 400.
// ci-SPLIT: wave w computes the FULL tile for kk=w (32 ci) per tap:
//   per tap per wave: 8 A-frag + 4 B-frag ds_reads, 32 MFMA  (0.375 rd/MFMA).
// Epilogue: LDS tree-reduction of the 4 K-partials, then waves 0/1 own
// co-halves for BN + store (PROJ=0) or fused 8-ch projection (PROJ=1).
// ===========================================================================
template <int PROJ>
__global__ __launch_bounds__(256) void conv_mfma(
    const char* __restrict__ actin,
    const char* __restrict__ wpl,         // 36 x 8192 B (this layer)
    const float* __restrict__ invshift_l, // 256 f32
    char* __restrict__ actout,            // PROJ=0
    const float* __restrict__ pw,         // PROJ=1: (8,128)
    const float* __restrict__ pb,         // (8)
    float* __restrict__ mf)               // (8,HW)
{
    __shared__ __align__(16) char smem[60416];
    char* IT = smem;                 // 27648 B : [6 rows][18 px][256 B]
    char* WT = smem + 27648;         // 32768 B : [4 kk][128 co][64 B]

    const int tid  = threadIdx.x;
    const int lane = tid & 63;
    const int w    = tid >> 6;       // wave = kk quarter
    const int g    = lane >> 4;
    const int i15  = lane & 15;

    const int bx = blockIdx.x;       // 0..9
    const int by = blockIdx.y;       // 0..39
    const int tx0 = bx * 16 - 1;
    const int ty0 = by * 4 - 1;

    // ---- prologue: input tile DMA (clamped) then weights tap 0
    for (int it = 0; it < 7; ++it) {
        int c = it * 256 + tid;
        if (c < 1728) {                       // whole waves (1728 % 64 == 0)
            int row  = c / 288;
            int rem  = c - row * 288;
            int px_i = rem >> 4;
            int bo   = (rem & 15) * 16;
            int cy = min(max(ty0 + row, 0), H - 1);
            int cx = min(max(tx0 + px_i, 0), W - 1);
            char* ldsb = IT + (it * 256 + (tid & ~63)) * 16;
            gload16(actin + cy * ROWB + cx * 256 + bo, ldsb);
        }
    }
#pragma unroll
    for (int it = 0; it < 8; ++it) {
        int c = it * 256 + tid;
        gload16(wpl + c * 16, WT + (it * 256 + (tid & ~63)) * 16);
    }
    asm volatile("s_waitcnt vmcnt(8)" ::: "memory");   // IT landed
    for (int c = tid; c < 1728; c += 256) {            // zero OOB borders
        int row  = c / 288;
        int rem  = c - row * 288;
        int px_i = rem >> 4;
        int gy = ty0 + row, gx = tx0 + px_i;
        if ((unsigned)gy >= (unsigned)H || (unsigned)gx >= (unsigned)W) {
            f32x4 z = {0.f, 0.f, 0.f, 0.f};
            *(f32x4*)(IT + c * 16) = z;
        }
    }

    f32x4 acc[8][4];
#pragma unroll
    for (int cf = 0; cf < 8; ++cf)
#pragma unroll
        for (int pf = 0; pf < 4; ++pf)
            acc[cf][pf] = (f32x4){0.f, 0.f, 0.f, 0.f};

    const int kb = w * 64 + g * 16;          // this wave's K-slice byte base

#pragma unroll
    for (int tap = 0; tap < 9; ++tap) {
        asm volatile("s_waitcnt vmcnt(0)" ::: "memory");
        LGKM0();
        BARRIER();                            // WT(tap) ready everywhere
        {
            const int r = tap / 3, s = tap - r * 3;
            const int keyb = ((i15 + s + 7) & 7) << 5;
            const char* wb = WT + w * 8192 + i15 * 64 + g * 16;
            bf16x8 a[8];
#pragma unroll
            for (int cf = 0; cf < 8; ++cf)
                a[cf] = *(const bf16x8*)(wb + cf * 1024);
            const char* ib = IT + (i15 + s) * 256 + (kb ^ keyb);
            bf16x8 b[4];
#pragma unroll
            for (int pf = 0; pf < 4; ++pf)
                b[pf] = *(const bf16x8*)(ib + (pf + r) * 4608);
#pragma unroll
            for (int cf = 0; cf < 8; ++cf)
#pragma unroll
                for (int pf = 0; pf < 4; ++pf)
                    acc[cf][pf] = __builtin_amdgcn_mfma_f32_16x16x32_bf16(
                        a[cf], b[pf], acc[cf][pf], 0, 0, 0);
        }
        BARRIER();                            // all waves done reading WT
        if (tap < 8) {
            const char* wtap = wpl + (tap + 1) * 32768;
#pragma unroll
            for (int it = 0; it < 8; ++it) {
                int c = it * 256 + tid;
                gload16(wtap + c * 16, WT + (it * 256 + (tid & ~63)) * 16);
            }
        }
    }

    // ---- cross-wave K-reduction (WT region reused as scratch) ------------
    char* redA = smem + 27648;            // 16 KB
    char* redB = smem + 27648 + 16384;    // 16 KB
    const int swz = (i15 & 7) << 4;
    // layout A/B rounds: [pfi(2)][px16][co128] f32, co-bytes XOR swz
#define REDAB(buf, pfi, cf) ((buf) + ((pfi) * 16 + i15) * 512 + (((cf) * 64 + g * 16) ^ swz))
    // round A: pf 0,1
    if (w == 2) { for (int cf = 0; cf < 8; ++cf) { *(f32x4*)REDAB(redA,0,cf) = acc[cf][0]; *(f32x4*)REDAB(redA,1,cf) = acc[cf][1]; } }
    if (w == 3) { for (int cf = 0; cf < 8; ++cf) { *(f32x4*)REDAB(redB,0,cf) = acc[cf][0]; *(f32x4*)REDAB(redB,1,cf) = acc[cf][1]; } }
    __syncthreads();
    if (w == 0) { for (int cf = 0; cf < 8; ++cf) { acc[cf][0] += *(f32x4*)REDAB(redA,0,cf); acc[cf][1] += *(f32x4*)REDAB(redA,1,cf); } }
    if (w == 1) { for (int cf = 0; cf < 8; ++cf) { acc[cf][0] += *(f32x4*)REDAB(redB,0,cf); acc[cf][1] += *(f32x4*)REDAB(redB,1,cf); } }
    __syncthreads();
    // round B: pf 2,3
    if (w == 2) { for (int cf = 0; cf < 8; ++cf) { *(f32x4*)REDAB(redA,0,cf) = acc[cf][2]; *(f32x4*)REDAB(redA,1,cf) = acc[cf][3]; } }
    if (w == 3) { for (int cf = 0; cf < 8; ++cf) { *(f32x4*)REDAB(redB,0,cf) = acc[cf][2]; *(f32x4*)REDAB(redB,1,cf) = acc[cf][3]; } }
    __syncthreads();
    if (w == 0) { for (int cf = 0; cf < 8; ++cf) { acc[cf][2] += *(f32x4*)REDAB(redA,0,cf); acc[cf][3] += *(f32x4*)REDAB(redA,1,cf); } }
    if (w == 1) { for (int cf = 0; cf < 8; ++cf) { acc[cf][2] += *(f32x4*)REDAB(redB,0,cf); acc[cf][3] += *(f32x4*)REDAB(redB,1,cf); } }
    __syncthreads();
    // round C: combine halves; layout [pf(4)][px16][co64]
#define REDC(buf, pf, cfq) ((buf) + ((pf) * 16 + i15) * 256 + (((cfq) * 64 + g * 16) ^ swz))
    if (w == 1) { for (int cf = 0; cf < 4; ++cf) for (int pf = 0; pf < 4; ++pf) *(f32x4*)REDC(redA, pf, cf) = acc[cf][pf]; }
    if (w == 0) { for (int cf = 4; cf < 8; ++cf) for (int pf = 0; pf < 4; ++pf) *(f32x4*)REDC(redB, pf, (cf - 4)) = acc[cf][pf]; }
    __syncthreads();
    if (w == 0) { for (int cf = 0; cf < 4; ++cf) for (int pf = 0; pf < 4; ++pf) acc[cf][pf] += *(f32x4*)REDC(redA, pf, cf); }
    if (w == 1) { for (int cf = 4; cf < 8; ++cf) for (int pf = 0; pf < 4; ++pf) acc[cf][pf] += *(f32x4*)REDC(redB, pf, (cf - 4)); }

    // ---- epilogue: waves 0/1 own co-halves --------------------------------
    if (PROJ == 0) {
        if (w < 2) {
            const int gx = bx * 16 + i15;
            const int keyo = (gx & 7) << 5;
            const int cf0 = w * 4;
#pragma unroll
            for (int cfq = 0; cfq < 4; ++cfq) {
                int cf = cf0 + cfq;
                int co0 = cf * 16 + g * 4;
                f32x4 inv4 = *(const f32x4*)&invshift_l[co0];
                f32x4 sh4  = *(const f32x4*)&invshift_l[128 + co0];
#pragma unroll
                for (int pf = 0; pf < 4; ++pf) {
                    int gy = by * 4 + pf;
                    f32x4 v = acc[cf][pf];
                    ushort4v o;
                    o.x = f2b(fmaxf(v.x * inv4.x + sh4.x, 0.f));
                    o.y = f2b(fmaxf(v.y * inv4.y + sh4.y, 0.f));
                    o.z = f2b(fmaxf(v.z * inv4.z + sh4.z, 0.f));
                    o.w = f2b(fmaxf(v.w * inv4.w + sh4.w, 0.f));
                    *(ushort4v*)(actout + gy * ROWB + gx * 256 + ((co0 * 2) ^ keyo)) = o;
                }
            }
        }
    } else {
        // fused projection: BN'd layer-4 acts -> actF (bf16, swizzled), then proj
        char* actF = smem;                      // 16 KB [64px][256B]  (IT dead)
        float* spw = (float*)(smem + 16384);    // 4 KB
        for (int i = tid; i < 1024; i += 256) spw[i] = pw[i];
        if (w < 2) {
            const int cf0 = w * 4;
#pragma unroll
            for (int cfq = 0; cfq < 4; ++cfq) {
                int cf = cf0 + cfq;
                int co0 = cf * 16 + g * 4;
                f32x4 inv4 = *(const f32x4*)&invshift_l[co0];
                f32x4 sh4  = *(const f32x4*)&invshift_l[128 + co0];
#pragma unroll
                for (int pf = 0; pf < 4; ++pf) {
                    int px = pf * 16 + i15;
                    f32x4 v = acc[cf][pf];
                    ushort4v o;
                    o.x = f2b(fmaxf(v.x * inv4.x + sh4.x, 0.f));
                    o.y = f2b(fmaxf(v.y * inv4.y + sh4.y, 0.f));
                    o.z = f2b(fmaxf(v.z * inv4.z + sh4.z, 0.f));
                    o.w = f2b(fmaxf(v.w * inv4.w + sh4.w, 0.f));
                    *(ushort4v*)(actF + px * 256 + ((co0 * 2) ^ ((px & 7) << 5))) = o;
                }
            }
        }
        __syncthreads();
        int px = tid & 63;
        int o0 = (tid >> 6) * 2;
        int key = (px & 7) << 5;
        float s0 = 0.f, s1 = 0.f;
#pragma unroll
        for (int cb = 0; cb < 16; ++cb) {
            ushort8v vv = *(const ushort8v*)(actF + px * 256 + ((cb * 16) ^ key));
#pragma unroll
            for (int j = 0; j < 8; ++j) {
                float f = b2f(vv[j]);
                int ci = cb * 8 + j;
                s0 += f * spw[o0 * 128 + ci];
                s1 += f * spw[(o0 + 1) * 128 + ci];
            }
        }
        int p = (by * 4 + (px >> 4)) * W + bx * 16 + (px & 15);
        mf[o0 * HW + p]       = s0 + pb[o0];
        mf[(o0 + 1) * HW + p] = s1 + pb[o0 + 1];
    }
#undef REDAB
#undef REDC
}

// ===========================================================================
// ctrl: controller conv at the K=100 detection points (fp32)
// ===========================================================================
__global__ __launch_bounds__(256) void ctrl_kernel(
    const float* __restrict__ feat, const float* __restrict__ cw,
    const float* __restrict__ cb, const int* __restrict__ det,
    float* __restrict__ params)
{
    __shared__ float patch[1152];
    const int tid = threadIdx.x;
    const int k = blockIdx.x;
    const int xk = det[2 * k];
    const int yk = det[2 * k + 1];

    for (int i = tid; i < 1152; i += 256) {
        int ci = i / 9;
        int rem = i - ci * 9;
        int r = rem / 3, s = rem - r * 3;
        int gy = yk + r - 1, gx = xk + s - 1;
        float v = 0.f;
        if ((unsigned)gy < (unsigned)H && (unsigned)gx < (unsigned)W)
            v = feat[ci * HW + gy * W + gx];
        patch[i] = v;
    }
    __syncthreads();

    if (tid < 169) {
        float acc = cb[tid];
        const float4* cw4 = (const float4*)&cw[tid * 1152];
        const float4* p4  = (const float4*)patch;
        for (int i = 0; i < 288; ++i) {
            float4 a = p4[i];
            float4 b = cw4[i];
            acc += a.x * b.x + a.y * b.y + a.z * b.z + a.w * b.w;
        }
        params[k * 169 + tid] = acc;
    }
}

// ===========================================================================
// head: 10 detections per block; mf read once, reused 10x.
// ===========================================================================
__global__ __launch_bounds__(256) void head_kernel(
    const float* __restrict__ mf, const float* __restrict__ params,
    const int* __restrict__ det, float* __restrict__ out)
{
    __shared__ float sp[1690];
    __shared__ int sdet[20];
    const int tid = threadIdx.x;
    const int kg = blockIdx.y;
    for (int i = tid; i < 1690; i += 256) sp[i] = params[kg * 1690 + i];
    if (tid < 20) sdet[tid] = det[kg * 20 + tid];
    __syncthreads();

    const int p = blockIdx.x * 256 + tid;
    const int x = p % W;
    const int y = p / W;
    const float fx = (float)(x * 4 + 2);
    const float fy = (float)(y * 4 + 2);

    float f[8];
#pragma unroll
    for (int o = 0; o < 8; ++o) f[o] = mf[o * HW + p];

#pragma unroll 2
    for (int j = 0; j < 10; ++j) {
        const float* spj = &sp[j * 169];
        const float rel0 = (float)(sdet[2 * j] * 4) - fx;
        const float rel1 = (float)(sdet[2 * j + 1] * 4) - fy;
        float h0[8];
#pragma unroll
        for (int o = 0; o < 8; ++o) {
            float a = spj[152 + o] + spj[o * 10] * rel0 + spj[o * 10 + 1] * rel1;
#pragma unroll
            for (int c = 0; c < 8; ++c) a += spj[o * 10 + 2 + c] * f[c];
            h0[o] = fmaxf(a, 0.f);
        }
        float h1[8];
#pragma unroll
        for (int o = 0; o < 8; ++o) {
            float a = spj[160 + o];
#pragma unroll
            for (int c = 0; c < 8; ++c) a += spj[80 + o * 8 + c] * h0[c];
            h1[o] = fmaxf(a, 0.f);
        }
        float r = spj[168];
#pragma unroll
        for (int c = 0; c < 8; ++c) r += spj[144 + c] * h1[c];
        out[(kg * 10 + j) * HW + p] = r;
    }
}

// ===========================================================================
extern "C" void kernel_launch(void* const* d_in, const int* in_sizes, int n_in,
                              void* d_out, int out_size, void* d_ws, size_t ws_size,
                              hipStream_t stream)
{
    const float* cnn    = (const float*)d_in[0];
    const float* towerw = (const float*)d_in[1];
    const float* gamma  = (const float*)d_in[2];
    const float* beta   = (const float*)d_in[3];
    const float* meanp  = (const float*)d_in[4];
    const float* varp   = (const float*)d_in[5];
    const float* projw  = (const float*)d_in[6];
    const float* projb  = (const float*)d_in[7];
    const float* ctrlw  = (const float*)d_in[8];
    const float* ctrlb  = (const float*)d_in[9];
    const int*   det    = (const int*)d_in[10];
    float* out = (float*)d_out;

    char*  outb     = (char*)d_out;
    char*  X        = outb;                          // 6,553,600 B
    char*  wbf      = outb + 6553600;                // 1,179,648 B
    float* invshift = (float*)(outb + 7733248);      // 4,096 B

    char*  Y      = (char*)d_ws;                     // 6,553,600 B
    float* mf     = (float*)((char*)d_ws + 6553600); // 819,200 B
    float* params = (float*)((char*)d_ws + 7372800); // 67,600 B

    const dim3 blk(256);

    prep_weights<<<dim3(256), blk, 0, stream>>>(towerw, gamma, beta, meanp, varp,
                                                wbf, invshift);
    prep_input<<<dim3(1600), blk, 0, stream>>>(cnn, X);

    const dim3 cgrid(10, 40);
    conv_mfma<0><<<cgrid, blk, 0, stream>>>(X, wbf + 0 * 294912, invshift + 0 * 256,
                                            Y, nullptr, nullptr, nullptr);
    conv_mfma<0><<<cgrid, blk, 0, stream>>>(Y, wbf + 1 * 294912, invshift + 1 * 256,
                                            X, nullptr, nullptr, nullptr);
    conv_mfma<0><<<cgrid, blk, 0, stream>>>(X, wbf + 2 * 294912, invshift + 2 * 256,
                                            Y, nullptr, nullptr, nullptr);
    conv_mfma<1><<<cgrid, blk, 0, stream>>>(Y, wbf + 3 * 294912, invshift + 3 * 256,
                                            nullptr, projw, projb, mf);

    ctrl_kernel<<<dim3(100), blk, 0, stream>>>(cnn, ctrlw, ctrlb, det, params);
    head_kernel<<<dim3(100, 10), blk, 0, stream>>>(mf, params, det, out);
}

// Round 9
// 421.456 us; speedup vs baseline: 1.0823x; 1.0823x over previous
//
#include <hip/hip_runtime.h>
#include <hip/hip_bf16.h>

#define H 160
#define W 160
#define HW 25600
#define ROWB 40960      // W * 256 bytes per NHWC row

typedef __attribute__((ext_vector_type(8))) short bf16x8;
typedef __attribute__((ext_vector_type(4))) float f32x4;
typedef __attribute__((ext_vector_type(8))) unsigned short ushort8v;
typedef __attribute__((ext_vector_type(4))) unsigned short ushort4v;

typedef __attribute__((address_space(1))) const unsigned int gu32;
typedef __attribute__((address_space(3))) unsigned int lu32;

__device__ __forceinline__ void gload16(const void* g, void* l) {
    __builtin_amdgcn_global_load_lds((gu32*)g, (lu32*)l, 16, 0, 0);
}

__device__ __forceinline__ unsigned short f2b(float f) {
    unsigned int u = __float_as_uint(f);
    unsigned int r = (u + 0x7fffu + ((u >> 16) & 1u)) >> 16;
    return (unsigned short)r;
}
__device__ __forceinline__ float b2f(unsigned short b) {
    return __uint_as_float(((unsigned int)b) << 16);
}

#define LGKM0() asm volatile("s_waitcnt lgkmcnt(0)" ::: "memory")
#define BARRIER() asm volatile("s_barrier" ::: "memory")

// ---------------------------------------------------------------------------
// d_out scratch layout (10,240,000 B; dead until head_kernel rewrites it):
//   [0, 6553600)        act X  (swizzled NHWC bf16)
//   [6553600, 7733248)  wbf: 4 layers x 36 planes x 8192 B ([tap][kk][co][64B])
//   [7733248, 7737344)  invshift: 4 layers x (inv[128], shift[128]) f32
// ws layout (7,440,400 B — proven budget):
//   [0, 6553600)        act Y
//   [6553600, 7372800)  mf (8 x 25600 f32)
//   [7372800, 7440400)  params (100 x 169 f32)
// ---------------------------------------------------------------------------

// ===========================================================================
// prep_weights (coalesced): thread = (l,co,ci) -> 65,536 threads = 256 blocks
// EXACT. Reads 9 contiguous fp32, writes bf16 planes [l][tap][kk][co][32ci].
// ===========================================================================
__global__ __launch_bounds__(256) void prep_weights(
    const float* __restrict__ tw,
    const float* __restrict__ gamma, const float* __restrict__ beta,
    const float* __restrict__ mean,  const float* __restrict__ var,
    char* __restrict__ wbf, float* __restrict__ invshift)
{
    int idx = blockIdx.x * 256 + threadIdx.x;     // 65,536 exact (256 blocks)
    int ci = idx & 127;
    int co = (idx >> 7) & 127;
    int l  = idx >> 14;                            // 0..3
    int kk = ci >> 5;
    int cw = ci & 31;
    const float* src = tw + ((l * 128 + co) * 128 + ci) * 9;
    char* dst = wbf + l * 294912 + kk * 8192 + co * 64 + cw * 2;
#pragma unroll
    for (int t = 0; t < 9; ++t)
        *(unsigned short*)(dst + t * 32768) = f2b(src[t]);

    if (blockIdx.x == 0) {
        for (int c = threadIdx.x; c < 512; c += 256) {
            int ll = c >> 7, ch = c & 127;
            float inv = gamma[ll * 128 + ch] * rsqrtf(var[ll * 128 + ch] + 1e-5f);
            float sh  = beta[ll * 128 + ch] - mean[ll * 128 + ch] * inv;
            invshift[ll * 256 + ch] = inv;
            invshift[ll * 256 + 128 + ch] = sh;
        }
    }
}

// ===========================================================================
// prep_input: cnn batch0 fp32 NCHW -> swizzled NHWC bf16 (act X)
// ===========================================================================
__global__ __launch_bounds__(256) void prep_input(
    const float* __restrict__ cnn, char* __restrict__ actX)
{
    int idx = blockIdx.x * 256 + threadIdx.x;   // 409,600 exact
    int cb = idx & 15;
    int p  = idx >> 4;
    int x  = p % W;
    int key = (x & 7) << 5;
    int ci0 = cb * 8;
    ushort8v o;
#pragma unroll
    for (int j = 0; j < 8; ++j)
        o[j] = f2b(cnn[(ci0 + j) * HW + p]);
    *(ushort8v*)(actX + p * 256 + ((cb * 16) ^ key)) = o;
}

// ===========================================================================
// conv_mfma v3b: 3x3 SAME conv 128->128 (+BN+ReLU).
// Block 256 thr / 4 waves, tile 128co x 64px. Grid (10,40).
// ci-SPLIT: wave w computes the FULL tile for kk=w per tap (0.375 rd/MFMA).
// v3 bug fixed: __launch_bounds__(256,2) -> 256-VGPR budget, no acc spill.
// MFMA loop: b[4] first, then two a[4] halves (peak live ~160 VGPR).
// ===========================================================================
template <int PROJ>
__global__ __launch_bounds__(256, 2) void conv_mfma(
    const char* __restrict__ actin,
    const char* __restrict__ wpl,         // 36 x 8192 B (this layer)
    const float* __restrict__ invshift_l, // 256 f32
    char* __restrict__ actout,            // PROJ=0
    const float* __restrict__ pw,         // PROJ=1: (8,128)
    const float* __restrict__ pb,         // (8)
    float* __restrict__ mf)               // (8,HW)
{
    __shared__ __align__(16) char smem[60416];
    char* IT = smem;                 // 27648 B : [6 rows][18 px][256 B]
    char* WT = smem + 27648;         // 32768 B : [4 kk][128 co][64 B]

    const int tid  = threadIdx.x;
    const int lane = tid & 63;
    const int w    = tid >> 6;       // wave = kk quarter
    const int g    = lane >> 4;
    const int i15  = lane & 15;

    const int bx = blockIdx.x;       // 0..9
    const int by = blockIdx.y;       // 0..39
    const int tx0 = bx * 16 - 1;
    const int ty0 = by * 4 - 1;

    // ---- prologue: input tile DMA (clamped) then weights tap 0
    for (int it = 0; it < 7; ++it) {
        int c = it * 256 + tid;
        if (c < 1728) {                       // whole waves (1728 % 64 == 0)
            int row  = c / 288;
            int rem  = c - row * 288;
            int px_i = rem >> 4;
            int bo   = (rem & 15) * 16;
            int cy = min(max(ty0 + row, 0), H - 1);
            int cx = min(max(tx0 + px_i, 0), W - 1);
            char* ldsb = IT + (it * 256 + (tid & ~63)) * 16;
            gload16(actin + cy * ROWB + cx * 256 + bo, ldsb);
        }
    }
#pragma unroll
    for (int it = 0; it < 8; ++it) {
        int c = it * 256 + tid;
        gload16(wpl + c * 16, WT + (it * 256 + (tid & ~63)) * 16);
    }
    asm volatile("s_waitcnt vmcnt(8)" ::: "memory");   // IT landed
    for (int c = tid; c < 1728; c += 256) {            // zero OOB borders
        int row  = c / 288;
        int rem  = c - row * 288;
        int px_i = rem >> 4;
        int gy = ty0 + row, gx = tx0 + px_i;
        if ((unsigned)gy >= (unsigned)H || (unsigned)gx >= (unsigned)W) {
            f32x4 z = {0.f, 0.f, 0.f, 0.f};
            *(f32x4*)(IT + c * 16) = z;
        }
    }

    f32x4 acc[8][4];
#pragma unroll
    for (int cf = 0; cf < 8; ++cf)
#pragma unroll
        for (int pf = 0; pf < 4; ++pf)
            acc[cf][pf] = (f32x4){0.f, 0.f, 0.f, 0.f};

    const int kb = w * 64 + g * 16;          // this wave's K-slice byte base

#pragma unroll
    for (int tap = 0; tap < 9; ++tap) {
        asm volatile("s_waitcnt vmcnt(0)" ::: "memory");
        LGKM0();
        BARRIER();                            // WT(tap) ready everywhere
        {
            const int r = tap / 3, s = tap - r * 3;
            const int keyb = ((i15 + s + 7) & 7) << 5;
            const char* ib = IT + (i15 + s) * 256 + (kb ^ keyb);
            bf16x8 b[4];
#pragma unroll
            for (int pf = 0; pf < 4; ++pf)
                b[pf] = *(const bf16x8*)(ib + (pf + r) * 4608);
            const char* wb = WT + w * 8192 + i15 * 64 + g * 16;
#pragma unroll
            for (int half = 0; half < 2; ++half) {
                bf16x8 a[4];
#pragma unroll
                for (int cq = 0; cq < 4; ++cq)
                    a[cq] = *(const bf16x8*)(wb + (half * 4 + cq) * 1024);
#pragma unroll
                for (int cq = 0; cq < 4; ++cq)
#pragma unroll
                    for (int pf = 0; pf < 4; ++pf)
                        acc[half * 4 + cq][pf] =
                            __builtin_amdgcn_mfma_f32_16x16x32_bf16(
                                a[cq], b[pf], acc[half * 4 + cq][pf], 0, 0, 0);
            }
        }
        BARRIER();                            // all waves done reading WT
        if (tap < 8) {
            const char* wtap = wpl + (tap + 1) * 32768;
#pragma unroll
            for (int it = 0; it < 8; ++it) {
                int c = it * 256 + tid;
                gload16(wtap + c * 16, WT + (it * 256 + (tid & ~63)) * 16);
            }
        }
    }

    // ---- cross-wave K-reduction (WT region reused as scratch) ------------
    char* redA = smem + 27648;            // 16 KB
    char* redB = smem + 27648 + 16384;    // 16 KB
    const int swz = (i15 & 7) << 4;
#define REDAB(buf, pfi, cf) ((buf) + ((pfi) * 16 + i15) * 512 + (((cf) * 64 + g * 16) ^ swz))
    // round A: pf 0,1
    if (w == 2) {
#pragma unroll
        for (int cf = 0; cf < 8; ++cf) { *(f32x4*)REDAB(redA,0,cf) = acc[cf][0]; *(f32x4*)REDAB(redA,1,cf) = acc[cf][1]; } }
    if (w == 3) {
#pragma unroll
        for (int cf = 0; cf < 8; ++cf) { *(f32x4*)REDAB(redB,0,cf) = acc[cf][0]; *(f32x4*)REDAB(redB,1,cf) = acc[cf][1]; } }
    __syncthreads();
    if (w == 0) {
#pragma unroll
        for (int cf = 0; cf < 8; ++cf) { acc[cf][0] += *(f32x4*)REDAB(redA,0,cf); acc[cf][1] += *(f32x4*)REDAB(redA,1,cf); } }
    if (w == 1) {
#pragma unroll
        for (int cf = 0; cf < 8; ++cf) { acc[cf][0] += *(f32x4*)REDAB(redB,0,cf); acc[cf][1] += *(f32x4*)REDAB(redB,1,cf); } }
    __syncthreads();
    // round B: pf 2,3
    if (w == 2) {
#pragma unroll
        for (int cf = 0; cf < 8; ++cf) { *(f32x4*)REDAB(redA,0,cf) = acc[cf][2]; *(f32x4*)REDAB(redA,1,cf) = acc[cf][3]; } }
    if (w == 3) {
#pragma unroll
        for (int cf = 0; cf < 8; ++cf) { *(f32x4*)REDAB(redB,0,cf) = acc[cf][2]; *(f32x4*)REDAB(redB,1,cf) = acc[cf][3]; } }
    __syncthreads();
    if (w == 0) {
#pragma unroll
        for (int cf = 0; cf < 8; ++cf) { acc[cf][2] += *(f32x4*)REDAB(redA,0,cf); acc[cf][3] += *(f32x4*)REDAB(redA,1,cf); } }
    if (w == 1) {
#pragma unroll
        for (int cf = 0; cf < 8; ++cf) { acc[cf][2] += *(f32x4*)REDAB(redB,0,cf); acc[cf][3] += *(f32x4*)REDAB(redB,1,cf); } }
    __syncthreads();
    // round C: combine halves; layout [pf(4)][px16][co64]
#define REDC(buf, pf, cfq) ((buf) + ((pf) * 16 + i15) * 256 + (((cfq) * 64 + g * 16) ^ swz))
    if (w == 1) {
#pragma unroll
        for (int cf = 0; cf < 4; ++cf)
#pragma unroll
            for (int pf = 0; pf < 4; ++pf) *(f32x4*)REDC(redA, pf, cf) = acc[cf][pf]; }
    if (w == 0) {
#pragma unroll
        for (int cf = 4; cf < 8; ++cf)
#pragma unroll
            for (int pf = 0; pf < 4; ++pf) *(f32x4*)REDC(redB, pf, (cf - 4)) = acc[cf][pf]; }
    __syncthreads();
    if (w == 0) {
#pragma unroll
        for (int cf = 0; cf < 4; ++cf)
#pragma unroll
            for (int pf = 0; pf < 4; ++pf) acc[cf][pf] += *(f32x4*)REDC(redA, pf, cf); }
    if (w == 1) {
#pragma unroll
        for (int cf = 4; cf < 8; ++cf)
#pragma unroll
            for (int pf = 0; pf < 4; ++pf) acc[cf][pf] += *(f32x4*)REDC(redB, pf, (cf - 4)); }

    // ---- epilogue: waves 0/1 own co-halves --------------------------------
    if (PROJ == 0) {
        if (w < 2) {
            const int gx = bx * 16 + i15;
            const int keyo = (gx & 7) << 5;
            const int cf0 = w * 4;
#pragma unroll
            for (int cfq = 0; cfq < 4; ++cfq) {
                int cf = cf0 + cfq;
                int co0 = cf * 16 + g * 4;
                f32x4 inv4 = *(const f32x4*)&invshift_l[co0];
                f32x4 sh4  = *(const f32x4*)&invshift_l[128 + co0];
#pragma unroll
                for (int pf = 0; pf < 4; ++pf) {
                    int gy = by * 4 + pf;
                    f32x4 v = acc[cf][pf];
                    ushort4v o;
                    o.x = f2b(fmaxf(v.x * inv4.x + sh4.x, 0.f));
                    o.y = f2b(fmaxf(v.y * inv4.y + sh4.y, 0.f));
                    o.z = f2b(fmaxf(v.z * inv4.z + sh4.z, 0.f));
                    o.w = f2b(fmaxf(v.w * inv4.w + sh4.w, 0.f));
                    *(ushort4v*)(actout + gy * ROWB + gx * 256 + ((co0 * 2) ^ keyo)) = o;
                }
            }
        }
    } else {
        // fused projection: BN'd layer-4 acts -> actF (bf16, swizzled), then proj
        char* actF = smem;                      // 16 KB [64px][256B]  (IT dead)
        float* spw = (float*)(smem + 16384);    // 4 KB
        for (int i = tid; i < 1024; i += 256) spw[i] = pw[i];
        if (w < 2) {
            const int cf0 = w * 4;
#pragma unroll
            for (int cfq = 0; cfq < 4; ++cfq) {
                int cf = cf0 + cfq;
                int co0 = cf * 16 + g * 4;
                f32x4 inv4 = *(const f32x4*)&invshift_l[co0];
                f32x4 sh4  = *(const f32x4*)&invshift_l[128 + co0];
#pragma unroll
                for (int pf = 0; pf < 4; ++pf) {
                    int px = pf * 16 + i15;
                    f32x4 v = acc[cf][pf];
                    ushort4v o;
                    o.x = f2b(fmaxf(v.x * inv4.x + sh4.x, 0.f));
                    o.y = f2b(fmaxf(v.y * inv4.y + sh4.y, 0.f));
                    o.z = f2b(fmaxf(v.z * inv4.z + sh4.z, 0.f));
                    o.w = f2b(fmaxf(v.w * inv4.w + sh4.w, 0.f));
                    *(ushort4v*)(actF + px * 256 + ((co0 * 2) ^ ((px & 7) << 5))) = o;
                }
            }
        }
        __syncthreads();
        int px = tid & 63;
        int o0 = (tid >> 6) * 2;
        int key = (px & 7) << 5;
        float s0 = 0.f, s1 = 0.f;
#pragma unroll
        for (int cb = 0; cb < 16; ++cb) {
            ushort8v vv = *(const ushort8v*)(actF + px * 256 + ((cb * 16) ^ key));
#pragma unroll
            for (int j = 0; j < 8; ++j) {
                float f = b2f(vv[j]);
                int ci = cb * 8 + j;
                s0 += f * spw[o0 * 128 + ci];
                s1 += f * spw[(o0 + 1) * 128 + ci];
            }
        }
        int p = (by * 4 + (px >> 4)) * W + bx * 16 + (px & 15);
        mf[o0 * HW + p]       = s0 + pb[o0];
        mf[(o0 + 1) * HW + p] = s1 + pb[o0 + 1];
    }
#undef REDAB
#undef REDC
}

// ===========================================================================
// ctrl: controller conv at the K=100 detection points (fp32)
// ===========================================================================
__global__ __launch_bounds__(256) void ctrl_kernel(
    const float* __restrict__ feat, const float* __restrict__ cw,
    const float* __restrict__ cb, const int* __restrict__ det,
    float* __restrict__ params)
{
    __shared__ float patch[1152];
    const int tid = threadIdx.x;
    const int k = blockIdx.x;
    const int xk = det[2 * k];
    const int yk = det[2 * k + 1];

    for (int i = tid; i < 1152; i += 256) {
        int ci = i / 9;
        int rem = i - ci * 9;
        int r = rem / 3, s = rem - r * 3;
        int gy = yk + r - 1, gx = xk + s - 1;
        float v = 0.f;
        if ((unsigned)gy < (unsigned)H && (unsigned)gx < (unsigned)W)
            v = feat[ci * HW + gy * W + gx];
        patch[i] = v;
    }
    __syncthreads();

    if (tid < 169) {
        float acc = cb[tid];
        const float4* cw4 = (const float4*)&cw[tid * 1152];
        const float4* p4  = (const float4*)patch;
        for (int i = 0; i < 288; ++i) {
            float4 a = p4[i];
            float4 b = cw4[i];
            acc += a.x * b.x + a.y * b.y + a.z * b.z + a.w * b.w;
        }
        params[k * 169 + tid] = acc;
    }
}

// ===========================================================================
// head: 10 detections per block; mf read once, reused 10x.
// ===========================================================================
__global__ __launch_bounds__(256) void head_kernel(
    const float* __restrict__ mf, const float* __restrict__ params,
    const int* __restrict__ det, float* __restrict__ out)
{
    __shared__ float sp[1690];
    __shared__ int sdet[20];
    const int tid = threadIdx.x;
    const int kg = blockIdx.y;
    for (int i = tid; i < 1690; i += 256) sp[i] = params[kg * 1690 + i];
    if (tid < 20) sdet[tid] = det[kg * 20 + tid];
    __syncthreads();

    const int p = blockIdx.x * 256 + tid;
    const int x = p % W;
    const int y = p / W;
    const float fx = (float)(x * 4 + 2);
    const float fy = (float)(y * 4 + 2);

    float f[8];
#pragma unroll
    for (int o = 0; o < 8; ++o) f[o] = mf[o * HW + p];

#pragma unroll 2
    for (int j = 0; j < 10; ++j) {
        const float* spj = &sp[j * 169];
        const float rel0 = (float)(sdet[2 * j] * 4) - fx;
        const float rel1 = (float)(sdet[2 * j + 1] * 4) - fy;
        float h0[8];
#pragma unroll
        for (int o = 0; o < 8; ++o) {
            float a = spj[152 + o] + spj[o * 10] * rel0 + spj[o * 10 + 1] * rel1;
#pragma unroll
            for (int c = 0; c < 8; ++c) a += spj[o * 10 + 2 + c] * f[c];
            h0[o] = fmaxf(a, 0.f);
        }
        float h1[8];
#pragma unroll
        for (int o = 0; o < 8; ++o) {
            float a = spj[160 + o];
#pragma unroll
            for (int c = 0; c < 8; ++c) a += spj[80 + o * 8 + c] * h0[c];
            h1[o] = fmaxf(a, 0.f);
        }
        float r = spj[168];
#pragma unroll
        for (int c = 0; c < 8; ++c) r += spj[144 + c] * h1[c];
        out[(kg * 10 + j) * HW + p] = r;
    }
}

// ===========================================================================
extern "C" void kernel_launch(void* const* d_in, const int* in_sizes, int n_in,
                              void* d_out, int out_size, void* d_ws, size_t ws_size,
                              hipStream_t stream)
{
    const float* cnn    = (const float*)d_in[0];
    const float* towerw = (const float*)d_in[1];
    const float* gamma  = (const float*)d_in[2];
    const float* beta   = (const float*)d_in[3];
    const float* meanp  = (const float*)d_in[4];
    const float* varp   = (const float*)d_in[5];
    const float* projw  = (const float*)d_in[6];
    const float* projb  = (const float*)d_in[7];
    const float* ctrlw  = (const float*)d_in[8];
    const float* ctrlb  = (const float*)d_in[9];
    const int*   det    = (const int*)d_in[10];
    float* out = (float*)d_out;

    char*  outb     = (char*)d_out;
    char*  X        = outb;                          // 6,553,600 B
    char*  wbf      = outb + 6553600;                // 1,179,648 B
    float* invshift = (float*)(outb + 7733248);      // 4,096 B

    char*  Y      = (char*)d_ws;                     // 6,553,600 B
    float* mf     = (float*)((char*)d_ws + 6553600); // 819,200 B
    float* params = (float*)((char*)d_ws + 7372800); // 67,600 B

    const dim3 blk(256);

    prep_weights<<<dim3(256), blk, 0, stream>>>(towerw, gamma, beta, meanp, varp,
                                                wbf, invshift);
    prep_input<<<dim3(1600), blk, 0, stream>>>(cnn, X);

    const dim3 cgrid(10, 40);
    conv_mfma<0><<<cgrid, blk, 0, stream>>>(X, wbf + 0 * 294912, invshift + 0 * 256,
                                            Y, nullptr, nullptr, nullptr);
    conv_mfma<0><<<cgrid, blk, 0, stream>>>(Y, wbf + 1 * 294912, invshift + 1 * 256,
                                            X, nullptr, nullptr, nullptr);
    conv_mfma<0><<<cgrid, blk, 0, stream>>>(X, wbf + 2 * 294912, invshift + 2 * 256,
                                            Y, nullptr, nullptr, nullptr);
    conv_mfma<1><<<cgrid, blk, 0, stream>>>(Y, wbf + 3 * 294912, invshift + 3 * 256,
                                            nullptr, projw, projb, mf);

    ctrl_kernel<<<dim3(100), blk, 0, stream>>>(cnn, ctrlw, ctrlb, det, params);
    head_kernel<<<dim3(100, 10), blk, 0, stream>>>(mf, params, det, out);
}

// Round 10
// 135.464 us; speedup vs baseline: 3.3673x; 3.1112x over previous
//
#include <hip/hip_runtime.h>
#include <hip/hip_bf16.h>

#define H 160
#define W 160
#define HW 25600
#define ROWB 40960      // W * 256 bytes per NHWC row

typedef __attribute__((ext_vector_type(8))) short bf16x8;
typedef __attribute__((ext_vector_type(4))) float f32x4;
typedef __attribute__((ext_vector_type(8))) unsigned short ushort8v;
typedef __attribute__((ext_vector_type(4))) unsigned short ushort4v;

typedef __attribute__((address_space(1))) const unsigned int gu32;
typedef __attribute__((address_space(3))) unsigned int lu32;

__device__ __forceinline__ void gload16(const void* g, void* l) {
    __builtin_amdgcn_global_load_lds((gu32*)g, (lu32*)l, 16, 0, 0);
}

__device__ __forceinline__ unsigned short f2b(float f) {
    unsigned int u = __float_as_uint(f);
    unsigned int r = (u + 0x7fffu + ((u >> 16) & 1u)) >> 16;
    return (unsigned short)r;
}
__device__ __forceinline__ float b2f(unsigned short b) {
    return __uint_as_float(((unsigned int)b) << 16);
}

#define LGKM0() asm volatile("s_waitcnt lgkmcnt(0)" ::: "memory")
#define BARRIER() asm volatile("s_barrier" ::: "memory")

// ---------------------------------------------------------------------------
// d_out scratch layout (10,240,000 B; dead until head_kernel rewrites it):
//   [0, 6553600)        act X  (swizzled NHWC bf16)
//   [6553600, 7733248)  wbf: 4 layers x 36 planes x 8192 B ([tap][kk][co][64B])
//   [7733248, 7737344)  invshift: 4 layers x (inv[128], shift[128]) f32
// ws layout (7,440,400 B — proven budget):
//   [0, 6553600)        act Y
//   [6553600, 7372800)  mf (8 x 25600 f32)
//   [7372800, 7440400)  params (100 x 169 f32)
// ---------------------------------------------------------------------------

// ===========================================================================
// prep_weights (coalesced): thread = (l,co,ci) -> 65,536 threads = 256 blocks
// EXACT. Reads 9 contiguous fp32, writes bf16 planes [l][tap][kk][co][32ci].
// ===========================================================================
__global__ __launch_bounds__(256) void prep_weights(
    const float* __restrict__ tw,
    const float* __restrict__ gamma, const float* __restrict__ beta,
    const float* __restrict__ mean,  const float* __restrict__ var,
    char* __restrict__ wbf, float* __restrict__ invshift)
{
    int idx = blockIdx.x * 256 + threadIdx.x;     // 65,536 exact (256 blocks)
    int ci = idx & 127;
    int co = (idx >> 7) & 127;
    int l  = idx >> 14;                            // 0..3
    int kk = ci >> 5;
    int cw = ci & 31;
    const float* src = tw + ((l * 128 + co) * 128 + ci) * 9;
    char* dst = wbf + l * 294912 + kk * 8192 + co * 64 + cw * 2;
#pragma unroll
    for (int t = 0; t < 9; ++t)
        *(unsigned short*)(dst + t * 32768) = f2b(src[t]);

    if (blockIdx.x == 0) {
        for (int c = threadIdx.x; c < 512; c += 256) {
            int ll = c >> 7, ch = c & 127;
            float inv = gamma[ll * 128 + ch] * rsqrtf(var[ll * 128 + ch] + 1e-5f);
            float sh  = beta[ll * 128 + ch] - mean[ll * 128 + ch] * inv;
            invshift[ll * 256 + ch] = inv;
            invshift[ll * 256 + 128 + ch] = sh;
        }
    }
}

// ===========================================================================
// prep_input: cnn batch0 fp32 NCHW -> swizzled NHWC bf16 (act X)
// ===========================================================================
__global__ __launch_bounds__(256) void prep_input(
    const float* __restrict__ cnn, char* __restrict__ actX)
{
    int idx = blockIdx.x * 256 + threadIdx.x;   // 409,600 exact
    int cb = idx & 15;
    int p  = idx >> 4;
    int x  = p % W;
    int key = (x & 7) << 5;
    int ci0 = cb * 8;
    ushort8v o;
#pragma unroll
    for (int j = 0; j < 8; ++j)
        o[j] = f2b(cnn[(ci0 + j) * HW + p]);
    *(ushort8v*)(actX + p * 256 + ((cb * 16) ^ key)) = o;
}

// ===========================================================================
// conv_mfma v3c: 3x3 SAME conv 128->128 (+BN+ReLU).
// Block 256 thr / 4 waves, tile 128co x 64px. Grid (10,40).
// ci-SPLIT: wave w computes the FULL tile for kk=w per tap (0.375 rd/MFMA).
// v3b bug fixed: epilogue indexed acc[w*4+cfq] with RUNTIME w -> whole acc
// array demoted to scratch (rule #20; 425 MB scratch traffic). Now all acc
// subscripts are compile-time; w appears only in branch conditions.
// ===========================================================================
template <int PROJ>
__global__ __launch_bounds__(256, 2) void conv_mfma(
    const char* __restrict__ actin,
    const char* __restrict__ wpl,         // 36 x 8192 B (this layer)
    const float* __restrict__ invshift_l, // 256 f32
    char* __restrict__ actout,            // PROJ=0
    const float* __restrict__ pw,         // PROJ=1: (8,128)
    const float* __restrict__ pb,         // (8)
    float* __restrict__ mf)               // (8,HW)
{
    __shared__ __align__(16) char smem[60416];
    char* IT = smem;                 // 27648 B : [6 rows][18 px][256 B]
    char* WT = smem + 27648;         // 32768 B : [4 kk][128 co][64 B]

    const int tid  = threadIdx.x;
    const int lane = tid & 63;
    const int w    = tid >> 6;       // wave = kk quarter
    const int g    = lane >> 4;
    const int i15  = lane & 15;

    const int bx = blockIdx.x;       // 0..9
    const int by = blockIdx.y;       // 0..39
    const int tx0 = bx * 16 - 1;
    const int ty0 = by * 4 - 1;

    // ---- prologue: input tile DMA (clamped) then weights tap 0
    for (int it = 0; it < 7; ++it) {
        int c = it * 256 + tid;
        if (c < 1728) {                       // whole waves (1728 % 64 == 0)
            int row  = c / 288;
            int rem  = c - row * 288;
            int px_i = rem >> 4;
            int bo   = (rem & 15) * 16;
            int cy = min(max(ty0 + row, 0), H - 1);
            int cx = min(max(tx0 + px_i, 0), W - 1);
            char* ldsb = IT + (it * 256 + (tid & ~63)) * 16;
            gload16(actin + cy * ROWB + cx * 256 + bo, ldsb);
        }
    }
#pragma unroll
    for (int it = 0; it < 8; ++it) {
        int c = it * 256 + tid;
        gload16(wpl + c * 16, WT + (it * 256 + (tid & ~63)) * 16);
    }
    asm volatile("s_waitcnt vmcnt(8)" ::: "memory");   // IT landed
    for (int c = tid; c < 1728; c += 256) {            // zero OOB borders
        int row  = c / 288;
        int rem  = c - row * 288;
        int px_i = rem >> 4;
        int gy = ty0 + row, gx = tx0 + px_i;
        if ((unsigned)gy >= (unsigned)H || (unsigned)gx >= (unsigned)W) {
            f32x4 z = {0.f, 0.f, 0.f, 0.f};
            *(f32x4*)(IT + c * 16) = z;
        }
    }

    f32x4 acc[8][4];
#pragma unroll
    for (int cf = 0; cf < 8; ++cf)
#pragma unroll
        for (int pf = 0; pf < 4; ++pf)
            acc[cf][pf] = (f32x4){0.f, 0.f, 0.f, 0.f};

    const int kb = w * 64 + g * 16;          // this wave's K-slice byte base

#pragma unroll
    for (int tap = 0; tap < 9; ++tap) {
        asm volatile("s_waitcnt vmcnt(0)" ::: "memory");
        LGKM0();
        BARRIER();                            // WT(tap) ready everywhere
        {
            const int r = tap / 3, s = tap - r * 3;
            const int keyb = ((i15 + s + 7) & 7) << 5;
            const char* ib = IT + (i15 + s) * 256 + (kb ^ keyb);
            bf16x8 b[4];
#pragma unroll
            for (int pf = 0; pf < 4; ++pf)
                b[pf] = *(const bf16x8*)(ib + (pf + r) * 4608);
            const char* wb = WT + w * 8192 + i15 * 64 + g * 16;
#pragma unroll
            for (int half = 0; half < 2; ++half) {
                bf16x8 a[4];
#pragma unroll
                for (int cq = 0; cq < 4; ++cq)
                    a[cq] = *(const bf16x8*)(wb + (half * 4 + cq) * 1024);
#pragma unroll
                for (int cq = 0; cq < 4; ++cq)
#pragma unroll
                    for (int pf = 0; pf < 4; ++pf)
                        acc[half * 4 + cq][pf] =
                            __builtin_amdgcn_mfma_f32_16x16x32_bf16(
                                a[cq], b[pf], acc[half * 4 + cq][pf], 0, 0, 0);
            }
        }
        BARRIER();                            // all waves done reading WT
        if (tap < 8) {
            const char* wtap = wpl + (tap + 1) * 32768;
#pragma unroll
            for (int it = 0; it < 8; ++it) {
                int c = it * 256 + tid;
                gload16(wtap + c * 16, WT + (it * 256 + (tid & ~63)) * 16);
            }
        }
    }

    // ---- cross-wave K-reduction (WT region reused as scratch) ------------
    char* redA = smem + 27648;            // 16 KB
    char* redB = smem + 27648 + 16384;    // 16 KB
    const int swz = (i15 & 7) << 4;
#define REDAB(buf, pfi, cf) ((buf) + ((pfi) * 16 + i15) * 512 + (((cf) * 64 + g * 16) ^ swz))
    // round A: pf 0,1
    if (w == 2) {
#pragma unroll
        for (int cf = 0; cf < 8; ++cf) { *(f32x4*)REDAB(redA,0,cf) = acc[cf][0]; *(f32x4*)REDAB(redA,1,cf) = acc[cf][1]; } }
    if (w == 3) {
#pragma unroll
        for (int cf = 0; cf < 8; ++cf) { *(f32x4*)REDAB(redB,0,cf) = acc[cf][0]; *(f32x4*)REDAB(redB,1,cf) = acc[cf][1]; } }
    __syncthreads();
    if (w == 0) {
#pragma unroll
        for (int cf = 0; cf < 8; ++cf) { acc[cf][0] += *(f32x4*)REDAB(redA,0,cf); acc[cf][1] += *(f32x4*)REDAB(redA,1,cf); } }
    if (w == 1) {
#pragma unroll
        for (int cf = 0; cf < 8; ++cf) { acc[cf][0] += *(f32x4*)REDAB(redB,0,cf); acc[cf][1] += *(f32x4*)REDAB(redB,1,cf); } }
    __syncthreads();
    // round B: pf 2,3
    if (w == 2) {
#pragma unroll
        for (int cf = 0; cf < 8; ++cf) { *(f32x4*)REDAB(redA,0,cf) = acc[cf][2]; *(f32x4*)REDAB(redA,1,cf) = acc[cf][3]; } }
    if (w == 3) {
#pragma unroll
        for (int cf = 0; cf < 8; ++cf) { *(f32x4*)REDAB(redB,0,cf) = acc[cf][2]; *(f32x4*)REDAB(redB,1,cf) = acc[cf][3]; } }
    __syncthreads();
    if (w == 0) {
#pragma unroll
        for (int cf = 0; cf < 8; ++cf) { acc[cf][2] += *(f32x4*)REDAB(redA,0,cf); acc[cf][3] += *(f32x4*)REDAB(redA,1,cf); } }
    if (w == 1) {
#pragma unroll
        for (int cf = 0; cf < 8; ++cf) { acc[cf][2] += *(f32x4*)REDAB(redB,0,cf); acc[cf][3] += *(f32x4*)REDAB(redB,1,cf); } }
    __syncthreads();
    // round C: combine halves; layout [pf(4)][px16][co64]
#define REDC(buf, pf, cfq) ((buf) + ((pf) * 16 + i15) * 256 + (((cfq) * 64 + g * 16) ^ swz))
    if (w == 1) {
#pragma unroll
        for (int cf = 0; cf < 4; ++cf)
#pragma unroll
            for (int pf = 0; pf < 4; ++pf) *(f32x4*)REDC(redA, pf, cf) = acc[cf][pf]; }
    if (w == 0) {
#pragma unroll
        for (int cf = 4; cf < 8; ++cf)
#pragma unroll
            for (int pf = 0; pf < 4; ++pf) *(f32x4*)REDC(redB, pf, (cf - 4)) = acc[cf][pf]; }
    __syncthreads();
    if (w == 0) {
#pragma unroll
        for (int cf = 0; cf < 4; ++cf)
#pragma unroll
            for (int pf = 0; pf < 4; ++pf) acc[cf][pf] += *(f32x4*)REDC(redA, pf, cf); }
    if (w == 1) {
#pragma unroll
        for (int cf = 4; cf < 8; ++cf)
#pragma unroll
            for (int pf = 0; pf < 4; ++pf) acc[cf][pf] += *(f32x4*)REDC(redB, pf, (cf - 4)); }

    // ---- epilogue: compile-time cf loop; wave ownership via CONDITION -----
    // (w==0 owns cf 0..3 / co 0..63; w==1 owns cf 4..7; waves 2,3 idle.)
    if (PROJ == 0) {
        const int gx = bx * 16 + i15;
        const int keyo = (gx & 7) << 5;
#pragma unroll
        for (int cf = 0; cf < 8; ++cf) {
            if ((cf >> 2) == w) {
                int co0 = cf * 16 + g * 4;
                f32x4 inv4 = *(const f32x4*)&invshift_l[co0];
                f32x4 sh4  = *(const f32x4*)&invshift_l[128 + co0];
#pragma unroll
                for (int pf = 0; pf < 4; ++pf) {
                    int gy = by * 4 + pf;
                    f32x4 v = acc[cf][pf];
                    ushort4v o;
                    o.x = f2b(fmaxf(v.x * inv4.x + sh4.x, 0.f));
                    o.y = f2b(fmaxf(v.y * inv4.y + sh4.y, 0.f));
                    o.z = f2b(fmaxf(v.z * inv4.z + sh4.z, 0.f));
                    o.w = f2b(fmaxf(v.w * inv4.w + sh4.w, 0.f));
                    *(ushort4v*)(actout + gy * ROWB + gx * 256 + ((co0 * 2) ^ keyo)) = o;
                }
            }
        }
    } else {
        // fused projection: BN'd layer-4 acts -> actF (bf16, swizzled), then proj
        char* actF = smem;                      // 16 KB [64px][256B]  (IT dead)
        float* spw = (float*)(smem + 16384);    // 4 KB
        for (int i = tid; i < 1024; i += 256) spw[i] = pw[i];
#pragma unroll
        for (int cf = 0; cf < 8; ++cf) {
            if ((cf >> 2) == w) {
                int co0 = cf * 16 + g * 4;
                f32x4 inv4 = *(const f32x4*)&invshift_l[co0];
                f32x4 sh4  = *(const f32x4*)&invshift_l[128 + co0];
#pragma unroll
                for (int pf = 0; pf < 4; ++pf) {
                    int px = pf * 16 + i15;
                    f32x4 v = acc[cf][pf];
                    ushort4v o;
                    o.x = f2b(fmaxf(v.x * inv4.x + sh4.x, 0.f));
                    o.y = f2b(fmaxf(v.y * inv4.y + sh4.y, 0.f));
                    o.z = f2b(fmaxf(v.z * inv4.z + sh4.z, 0.f));
                    o.w = f2b(fmaxf(v.w * inv4.w + sh4.w, 0.f));
                    *(ushort4v*)(actF + px * 256 + ((co0 * 2) ^ ((px & 7) << 5))) = o;
                }
            }
        }
        __syncthreads();
        int px = tid & 63;
        int o0 = (tid >> 6) * 2;
        int key = (px & 7) << 5;
        float s0 = 0.f, s1 = 0.f;
#pragma unroll
        for (int cb = 0; cb < 16; ++cb) {
            ushort8v vv = *(const ushort8v*)(actF + px * 256 + ((cb * 16) ^ key));
#pragma unroll
            for (int j = 0; j < 8; ++j) {
                float f = b2f(vv[j]);
                int ci = cb * 8 + j;
                s0 += f * spw[o0 * 128 + ci];
                s1 += f * spw[(o0 + 1) * 128 + ci];
            }
        }
        int p = (by * 4 + (px >> 4)) * W + bx * 16 + (px & 15);
        mf[o0 * HW + p]       = s0 + pb[o0];
        mf[(o0 + 1) * HW + p] = s1 + pb[o0 + 1];
    }
#undef REDAB
#undef REDC
}

// ===========================================================================
// ctrl: controller conv at the K=100 detection points (fp32)
// ===========================================================================
__global__ __launch_bounds__(256) void ctrl_kernel(
    const float* __restrict__ feat, const float* __restrict__ cw,
    const float* __restrict__ cb, const int* __restrict__ det,
    float* __restrict__ params)
{
    __shared__ float patch[1152];
    const int tid = threadIdx.x;
    const int k = blockIdx.x;
    const int xk = det[2 * k];
    const int yk = det[2 * k + 1];

    for (int i = tid; i < 1152; i += 256) {
        int ci = i / 9;
        int rem = i - ci * 9;
        int r = rem / 3, s = rem - r * 3;
        int gy = yk + r - 1, gx = xk + s - 1;
        float v = 0.f;
        if ((unsigned)gy < (unsigned)H && (unsigned)gx < (unsigned)W)
            v = feat[ci * HW + gy * W + gx];
        patch[i] = v;
    }
    __syncthreads();

    if (tid < 169) {
        float acc = cb[tid];
        const float4* cw4 = (const float4*)&cw[tid * 1152];
        const float4* p4  = (const float4*)patch;
        for (int i = 0; i < 288; ++i) {
            float4 a = p4[i];
            float4 b = cw4[i];
            acc += a.x * b.x + a.y * b.y + a.z * b.z + a.w * b.w;
        }
        params[k * 169 + tid] = acc;
    }
}

// ===========================================================================
// head: 10 detections per block; mf read once, reused 10x.
// ===========================================================================
__global__ __launch_bounds__(256) void head_kernel(
    const float* __restrict__ mf, const float* __restrict__ params,
    const int* __restrict__ det, float* __restrict__ out)
{
    __shared__ float sp[1690];
    __shared__ int sdet[20];
    const int tid = threadIdx.x;
    const int kg = blockIdx.y;
    for (int i = tid; i < 1690; i += 256) sp[i] = params[kg * 1690 + i];
    if (tid < 20) sdet[tid] = det[kg * 20 + tid];
    __syncthreads();

    const int p = blockIdx.x * 256 + tid;
    const int x = p % W;
    const int y = p / W;
    const float fx = (float)(x * 4 + 2);
    const float fy = (float)(y * 4 + 2);

    float f[8];
#pragma unroll
    for (int o = 0; o < 8; ++o) f[o] = mf[o * HW + p];

#pragma unroll 2
    for (int j = 0; j < 10; ++j) {
        const float* spj = &sp[j * 169];
        const float rel0 = (float)(sdet[2 * j] * 4) - fx;
        const float rel1 = (float)(sdet[2 * j + 1] * 4) - fy;
        float h0[8];
#pragma unroll
        for (int o = 0; o < 8; ++o) {
            float a = spj[152 + o] + spj[o * 10] * rel0 + spj[o * 10 + 1] * rel1;
#pragma unroll
            for (int c = 0; c < 8; ++c) a += spj[o * 10 + 2 + c] * f[c];
            h0[o] = fmaxf(a, 0.f);
        }
        float h1[8];
#pragma unroll
        for (int o = 0; o < 8; ++o) {
            float a = spj[160 + o];
#pragma unroll
            for (int c = 0; c < 8; ++c) a += spj[80 + o * 8 + c] * h0[c];
            h1[o] = fmaxf(a, 0.f);
        }
        float r = spj[168];
#pragma unroll
        for (int c = 0; c < 8; ++c) r += spj[144 + c] * h1[c];
        out[(kg * 10 + j) * HW + p] = r;
    }
}

// ===========================================================================
extern "C" void kernel_launch(void* const* d_in, const int* in_sizes, int n_in,
                              void* d_out, int out_size, void* d_ws, size_t ws_size,
                              hipStream_t stream)
{
    const float* cnn    = (const float*)d_in[0];
    const float* towerw = (const float*)d_in[1];
    const float* gamma  = (const float*)d_in[2];
    const float* beta   = (const float*)d_in[3];
    const float* meanp  = (const float*)d_in[4];
    const float* varp   = (const float*)d_in[5];
    const float* projw  = (const float*)d_in[6];
    const float* projb  = (const float*)d_in[7];
    const float* ctrlw  = (const float*)d_in[8];
    const float* ctrlb  = (const float*)d_in[9];
    const int*   det    = (const int*)d_in[10];
    float* out = (float*)d_out;

    char*  outb     = (char*)d_out;
    char*  X        = outb;                          // 6,553,600 B
    char*  wbf      = outb + 6553600;                // 1,179,648 B
    float* invshift = (float*)(outb + 7733248);      // 4,096 B

    char*  Y      = (char*)d_ws;                     // 6,553,600 B
    float* mf     = (float*)((char*)d_ws + 6553600); // 819,200 B
    float* params = (float*)((char*)d_ws + 7372800); // 67,600 B

    const dim3 blk(256);

    prep_weights<<<dim3(256), blk, 0, stream>>>(towerw, gamma, beta, meanp, varp,
                                                wbf, invshift);
    prep_input<<<dim3(1600), blk, 0, stream>>>(cnn, X);

    const dim3 cgrid(10, 40);
    conv_mfma<0><<<cgrid, blk, 0, stream>>>(X, wbf + 0 * 294912, invshift + 0 * 256,
                                            Y, nullptr, nullptr, nullptr);
    conv_mfma<0><<<cgrid, blk, 0, stream>>>(Y, wbf + 1 * 294912, invshift + 1 * 256,
                                            X, nullptr, nullptr, nullptr);
    conv_mfma<0><<<cgrid, blk, 0, stream>>>(X, wbf + 2 * 294912, invshift + 2 * 256,
                                            Y, nullptr, nullptr, nullptr);
    conv_mfma<1><<<cgrid, blk, 0, stream>>>(Y, wbf + 3 * 294912, invshift + 3 * 256,
                                            nullptr, projw, projb, mf);

    ctrl_kernel<<<dim3(100), blk, 0, stream>>>(cnn, ctrlw, ctrlb, det, params);
    head_kernel<<<dim3(100, 10), blk, 0, stream>>>(mf, params, det, out);
}

// Round 11
// 133.833 us; speedup vs baseline: 3.4084x; 1.0122x over previous
//
#include <hip/hip_runtime.h>
#include <hip/hip_bf16.h>

#define H 160
#define W 160
#define HW 25600
#define ROWB 40960      // W * 256 bytes per NHWC row

typedef __attribute__((ext_vector_type(8))) short bf16x8;
typedef __attribute__((ext_vector_type(4))) float f32x4;
typedef __attribute__((ext_vector_type(8))) unsigned short ushort8v;
typedef __attribute__((ext_vector_type(4))) unsigned short ushort4v;

typedef __attribute__((address_space(1))) const unsigned int gu32;
typedef __attribute__((address_space(3))) unsigned int lu32;

__device__ __forceinline__ void gload16(const void* g, void* l) {
    __builtin_amdgcn_global_load_lds((gu32*)g, (lu32*)l, 16, 0, 0);
}

__device__ __forceinline__ unsigned short f2b(float f) {
    unsigned int u = __float_as_uint(f);
    unsigned int r = (u + 0x7fffu + ((u >> 16) & 1u)) >> 16;
    return (unsigned short)r;
}
__device__ __forceinline__ float b2f(unsigned short b) {
    return __uint_as_float(((unsigned int)b) << 16);
}

#define LGKM0() asm volatile("s_waitcnt lgkmcnt(0)" ::: "memory")
#define BARRIER() asm volatile("s_barrier" ::: "memory")

// ---------------------------------------------------------------------------
// Activation global format (16-B-slot swizzle, key = x&15):
//   pixel p=(y,x): 256 B; 16-B slot for ci-block cb stored at slot cb^(x&15).
// Weight planes: [l][tap] 32768 B = [co][256 B]; slot for ci16=ci/8 stored at
//   slot ci16^(co&15).  Both are read conflict-free by v4's lane patterns.
// d_out scratch: [0,6553600) act X | [6553600,7733248) wbf | [7733248,+4KB) BN
// ws: [0,6553600) act Y | mf 819200 B | params 67600 B   (7,440,400 proven)
// ---------------------------------------------------------------------------

// ===========================================================================
// prep_weights: thread = (l,co,ci) -> 65,536 threads = 256 blocks EXACT.
// ===========================================================================
__global__ __launch_bounds__(256) void prep_weights(
    const float* __restrict__ tw,
    const float* __restrict__ gamma, const float* __restrict__ beta,
    const float* __restrict__ mean,  const float* __restrict__ var,
    char* __restrict__ wbf, float* __restrict__ invshift)
{
    int idx = blockIdx.x * 256 + threadIdx.x;     // 65,536 exact
    int ci = idx & 127;
    int co = (idx >> 7) & 127;
    int l  = idx >> 14;                            // 0..3
    int slot = (ci >> 3) ^ (co & 15);
    const float* src = tw + ((l * 128 + co) * 128 + ci) * 9;
    char* dst = wbf + l * 294912 + co * 256 + slot * 16 + (ci & 7) * 2;
#pragma unroll
    for (int t = 0; t < 9; ++t)
        *(unsigned short*)(dst + t * 32768) = f2b(src[t]);

    if (blockIdx.x == 0) {
        for (int c = threadIdx.x; c < 512; c += 256) {
            int ll = c >> 7, ch = c & 127;
            float inv = gamma[ll * 128 + ch] * rsqrtf(var[ll * 128 + ch] + 1e-5f);
            float sh  = beta[ll * 128 + ch] - mean[ll * 128 + ch] * inv;
            invshift[ll * 256 + ch] = inv;
            invshift[ll * 256 + 128 + ch] = sh;
        }
    }
}

// ===========================================================================
// prep_input: cnn batch0 fp32 NCHW -> swizzled NHWC bf16 (act X), key x&15
// ===========================================================================
__global__ __launch_bounds__(256) void prep_input(
    const float* __restrict__ cnn, char* __restrict__ actX)
{
    int idx = blockIdx.x * 256 + threadIdx.x;   // 409,600 exact
    int cb = idx & 15;
    int p  = idx >> 4;
    int x  = p % W;
    int ci0 = cb * 8;
    ushort8v o;
#pragma unroll
    for (int j = 0; j < 8; ++j)
        o[j] = f2b(cnn[(ci0 + j) * HW + p]);
    *(ushort8v*)(actX + p * 256 + ((cb ^ (x & 15)) * 16)) = o;
}

// ===========================================================================
// conv_mfma v4 = v3c + conflict-free 16B-slot swizzles.
// Block 256 thr / 4 waves, tile 128co x 64px. Grid (10,40).
// ci-SPLIT: wave w computes the FULL tile for kk=w per tap (0.375 rd/MFMA).
// A-read: WT[(cf*16+i15)*256 + ((w*4+g)^i15)*16]      -> 16 slots, 2/bank-free
// B-read: IT[row*256 + ((w*4+g)^((i15+s+15)&15))*16]  -> conflict-free
// ===========================================================================
template <int PROJ>
__global__ __launch_bounds__(256, 2) void conv_mfma(
    const char* __restrict__ actin,
    const char* __restrict__ wpl,         // 9 x 32768 B (this layer)
    const float* __restrict__ invshift_l, // 256 f32
    char* __restrict__ actout,            // PROJ=0
    const float* __restrict__ pw,         // PROJ=1: (8,128)
    const float* __restrict__ pb,         // (8)
    float* __restrict__ mf)               // (8,HW)
{
    __shared__ __align__(16) char smem[60416];
    char* IT = smem;                 // 27648 B : [6 rows][18 px][256 B]
    char* WT = smem + 27648;         // 32768 B : [128 co][256 B]

    const int tid  = threadIdx.x;
    const int lane = tid & 63;
    const int w    = tid >> 6;       // wave = kk quarter
    const int g    = lane >> 4;
    const int i15  = lane & 15;

    const int bx = blockIdx.x;       // 0..9
    const int by = blockIdx.y;       // 0..39
    const int tx0 = bx * 16 - 1;
    const int ty0 = by * 4 - 1;

    // ---- prologue: input tile DMA (clamped) then weights tap 0
    for (int it = 0; it < 7; ++it) {
        int c = it * 256 + tid;
        if (c < 1728) {                       // whole waves (1728 % 64 == 0)
            int row  = c / 288;
            int rem  = c - row * 288;
            int px_i = rem >> 4;
            int bo   = (rem & 15) * 16;
            int cy = min(max(ty0 + row, 0), H - 1);
            int cx = min(max(tx0 + px_i, 0), W - 1);
            char* ldsb = IT + (it * 256 + (tid & ~63)) * 16;
            gload16(actin + cy * ROWB + cx * 256 + bo, ldsb);
        }
    }
#pragma unroll
    for (int it = 0; it < 8; ++it) {
        int c = it * 256 + tid;
        gload16(wpl + c * 16, WT + (it * 256 + (tid & ~63)) * 16);
    }
    asm volatile("s_waitcnt vmcnt(8)" ::: "memory");   // IT landed
    for (int c = tid; c < 1728; c += 256) {            // zero OOB borders
        int row  = c / 288;
        int rem  = c - row * 288;
        int px_i = rem >> 4;
        int gy = ty0 + row, gx = tx0 + px_i;
        if ((unsigned)gy >= (unsigned)H || (unsigned)gx >= (unsigned)W) {
            f32x4 z = {0.f, 0.f, 0.f, 0.f};
            *(f32x4*)(IT + c * 16) = z;
        }
    }

    f32x4 acc[8][4];
#pragma unroll
    for (int cf = 0; cf < 8; ++cf)
#pragma unroll
        for (int pf = 0; pf < 4; ++pf)
            acc[cf][pf] = (f32x4){0.f, 0.f, 0.f, 0.f};

    const int aoff = i15 * 256 + (((w * 4 + g) ^ i15) * 16);  // lane A offset

#pragma unroll
    for (int tap = 0; tap < 9; ++tap) {
        asm volatile("s_waitcnt vmcnt(0)" ::: "memory");
        LGKM0();
        BARRIER();                            // WT(tap) ready everywhere
        {
            const int r = tap / 3, s = tap - r * 3;
            const int slotb = ((w * 4 + g) ^ ((i15 + s + 15) & 15)) * 16;
            const char* ib = IT + (i15 + s) * 256 + slotb;
            bf16x8 b[4];
#pragma unroll
            for (int pf = 0; pf < 4; ++pf)
                b[pf] = *(const bf16x8*)(ib + (pf + r) * 4608);
            const char* wb = WT + aoff;
#pragma unroll
            for (int half = 0; half < 2; ++half) {
                bf16x8 a[4];
#pragma unroll
                for (int cq = 0; cq < 4; ++cq)
                    a[cq] = *(const bf16x8*)(wb + (half * 4 + cq) * 4096);
#pragma unroll
                for (int cq = 0; cq < 4; ++cq)
#pragma unroll
                    for (int pf = 0; pf < 4; ++pf)
                        acc[half * 4 + cq][pf] =
                            __builtin_amdgcn_mfma_f32_16x16x32_bf16(
                                a[cq], b[pf], acc[half * 4 + cq][pf], 0, 0, 0);
            }
        }
        BARRIER();                            // all waves done reading WT
        if (tap < 8) {
            const char* wtap = wpl + (tap + 1) * 32768;
#pragma unroll
            for (int it = 0; it < 8; ++it) {
                int c = it * 256 + tid;
                gload16(wtap + c * 16, WT + (it * 256 + (tid & ~63)) * 16);
            }
        }
    }

    // ---- cross-wave K-reduction (WT region reused as scratch) ------------
    char* redA = smem + 27648;            // 16 KB
    char* redB = smem + 27648 + 16384;    // 16 KB
    const int swz = (i15 & 7) << 4;
#define REDAB(buf, pfi, cf) ((buf) + ((pfi) * 16 + i15) * 512 + (((cf) * 64 + g * 16) ^ swz))
    if (w == 2) {
#pragma unroll
        for (int cf = 0; cf < 8; ++cf) { *(f32x4*)REDAB(redA,0,cf) = acc[cf][0]; *(f32x4*)REDAB(redA,1,cf) = acc[cf][1]; } }
    if (w == 3) {
#pragma unroll
        for (int cf = 0; cf < 8; ++cf) { *(f32x4*)REDAB(redB,0,cf) = acc[cf][0]; *(f32x4*)REDAB(redB,1,cf) = acc[cf][1]; } }
    __syncthreads();
    if (w == 0) {
#pragma unroll
        for (int cf = 0; cf < 8; ++cf) { acc[cf][0] += *(f32x4*)REDAB(redA,0,cf); acc[cf][1] += *(f32x4*)REDAB(redA,1,cf); } }
    if (w == 1) {
#pragma unroll
        for (int cf = 0; cf < 8; ++cf) { acc[cf][0] += *(f32x4*)REDAB(redB,0,cf); acc[cf][1] += *(f32x4*)REDAB(redB,1,cf); } }
    __syncthreads();
    if (w == 2) {
#pragma unroll
        for (int cf = 0; cf < 8; ++cf) { *(f32x4*)REDAB(redA,0,cf) = acc[cf][2]; *(f32x4*)REDAB(redA,1,cf) = acc[cf][3]; } }
    if (w == 3) {
#pragma unroll
        for (int cf = 0; cf < 8; ++cf) { *(f32x4*)REDAB(redB,0,cf) = acc[cf][2]; *(f32x4*)REDAB(redB,1,cf) = acc[cf][3]; } }
    __syncthreads();
    if (w == 0) {
#pragma unroll
        for (int cf = 0; cf < 8; ++cf) { acc[cf][2] += *(f32x4*)REDAB(redA,0,cf); acc[cf][3] += *(f32x4*)REDAB(redA,1,cf); } }
    if (w == 1) {
#pragma unroll
        for (int cf = 0; cf < 8; ++cf) { acc[cf][2] += *(f32x4*)REDAB(redB,0,cf); acc[cf][3] += *(f32x4*)REDAB(redB,1,cf); } }
    __syncthreads();
#define REDC(buf, pf, cfq) ((buf) + ((pf) * 16 + i15) * 256 + (((cfq) * 64 + g * 16) ^ swz))
    if (w == 1) {
#pragma unroll
        for (int cf = 0; cf < 4; ++cf)
#pragma unroll
            for (int pf = 0; pf < 4; ++pf) *(f32x4*)REDC(redA, pf, cf) = acc[cf][pf]; }
    if (w == 0) {
#pragma unroll
        for (int cf = 4; cf < 8; ++cf)
#pragma unroll
            for (int pf = 0; pf < 4; ++pf) *(f32x4*)REDC(redB, pf, (cf - 4)) = acc[cf][pf]; }
    __syncthreads();
    if (w == 0) {
#pragma unroll
        for (int cf = 0; cf < 4; ++cf)
#pragma unroll
            for (int pf = 0; pf < 4; ++pf) acc[cf][pf] += *(f32x4*)REDC(redA, pf, cf); }
    if (w == 1) {
#pragma unroll
        for (int cf = 4; cf < 8; ++cf)
#pragma unroll
            for (int pf = 0; pf < 4; ++pf) acc[cf][pf] += *(f32x4*)REDC(redB, pf, (cf - 4)); }

    // ---- epilogue: compile-time cf loop; wave ownership via CONDITION -----
    if (PROJ == 0) {
        const int gx = bx * 16 + i15;      // gx & 15 == i15
#pragma unroll
        for (int cf = 0; cf < 8; ++cf) {
            if ((cf >> 2) == w) {
                int co0 = cf * 16 + g * 4;
                int sbyte = (((cf * 2 + (g >> 1)) ^ i15) * 16) + (g & 1) * 8;
                f32x4 inv4 = *(const f32x4*)&invshift_l[co0];
                f32x4 sh4  = *(const f32x4*)&invshift_l[128 + co0];
#pragma unroll
                for (int pf = 0; pf < 4; ++pf) {
                    int gy = by * 4 + pf;
                    f32x4 v = acc[cf][pf];
                    ushort4v o;
                    o.x = f2b(fmaxf(v.x * inv4.x + sh4.x, 0.f));
                    o.y = f2b(fmaxf(v.y * inv4.y + sh4.y, 0.f));
                    o.z = f2b(fmaxf(v.z * inv4.z + sh4.z, 0.f));
                    o.w = f2b(fmaxf(v.w * inv4.w + sh4.w, 0.f));
                    *(ushort4v*)(actout + gy * ROWB + gx * 256 + sbyte) = o;
                }
            }
        }
    } else {
        // fused projection: BN'd layer-4 acts -> actF (bf16, internal swizzle)
        char* actF = smem;                      // 16 KB [64px][256B]  (IT dead)
        float* spw = (float*)(smem + 16384);    // 4 KB
        for (int i = tid; i < 1024; i += 256) spw[i] = pw[i];
#pragma unroll
        for (int cf = 0; cf < 8; ++cf) {
            if ((cf >> 2) == w) {
                int co0 = cf * 16 + g * 4;
                f32x4 inv4 = *(const f32x4*)&invshift_l[co0];
                f32x4 sh4  = *(const f32x4*)&invshift_l[128 + co0];
#pragma unroll
                for (int pf = 0; pf < 4; ++pf) {
                    int px = pf * 16 + i15;
                    f32x4 v = acc[cf][pf];
                    ushort4v o;
                    o.x = f2b(fmaxf(v.x * inv4.x + sh4.x, 0.f));
                    o.y = f2b(fmaxf(v.y * inv4.y + sh4.y, 0.f));
                    o.z = f2b(fmaxf(v.z * inv4.z + sh4.z, 0.f));
                    o.w = f2b(fmaxf(v.w * inv4.w + sh4.w, 0.f));
                    *(ushort4v*)(actF + px * 256 + ((co0 * 2) ^ ((px & 7) << 5))) = o;
                }
            }
        }
        __syncthreads();
        int px = tid & 63;
        int o0 = (tid >> 6) * 2;
        int key = (px & 7) << 5;
        float s0 = 0.f, s1 = 0.f;
#pragma unroll
        for (int cb = 0; cb < 16; ++cb) {
            ushort8v vv = *(const ushort8v*)(actF + px * 256 + ((cb * 16) ^ key));
#pragma unroll
            for (int j = 0; j < 8; ++j) {
                float f = b2f(vv[j]);
                int ci = cb * 8 + j;
                s0 += f * spw[o0 * 128 + ci];
                s1 += f * spw[(o0 + 1) * 128 + ci];
            }
        }
        int p = (by * 4 + (px >> 4)) * W + bx * 16 + (px & 15);
        mf[o0 * HW + p]       = s0 + pb[o0];
        mf[(o0 + 1) * HW + p] = s1 + pb[o0 + 1];
    }
#undef REDAB
#undef REDC
}

// ===========================================================================
// ctrl: controller conv at the K=100 detection points (fp32)
// ===========================================================================
__global__ __launch_bounds__(256) void ctrl_kernel(
    const float* __restrict__ feat, const float* __restrict__ cw,
    const float* __restrict__ cb, const int* __restrict__ det,
    float* __restrict__ params)
{
    __shared__ float patch[1152];
    const int tid = threadIdx.x;
    const int k = blockIdx.x;
    const int xk = det[2 * k];
    const int yk = det[2 * k + 1];

    for (int i = tid; i < 1152; i += 256) {
        int ci = i / 9;
        int rem = i - ci * 9;
        int r = rem / 3, s = rem - r * 3;
        int gy = yk + r - 1, gx = xk + s - 1;
        float v = 0.f;
        if ((unsigned)gy < (unsigned)H && (unsigned)gx < (unsigned)W)
            v = feat[ci * HW + gy * W + gx];
        patch[i] = v;
    }
    __syncthreads();

    if (tid < 169) {
        float acc = cb[tid];
        const float4* cw4 = (const float4*)&cw[tid * 1152];
        const float4* p4  = (const float4*)patch;
        for (int i = 0; i < 288; ++i) {
            float4 a = p4[i];
            float4 b = cw4[i];
            acc += a.x * b.x + a.y * b.y + a.z * b.z + a.w * b.w;
        }
        params[k * 169 + tid] = acc;
    }
}

// ===========================================================================
// head: 10 detections per block; mf read once, reused 10x.
// ===========================================================================
__global__ __launch_bounds__(256) void head_kernel(
    const float* __restrict__ mf, const float* __restrict__ params,
    const int* __restrict__ det, float* __restrict__ out)
{
    __shared__ float sp[1690];
    __shared__ int sdet[20];
    const int tid = threadIdx.x;
    const int kg = blockIdx.y;
    for (int i = tid; i < 1690; i += 256) sp[i] = params[kg * 1690 + i];
    if (tid < 20) sdet[tid] = det[kg * 20 + tid];
    __syncthreads();

    const int p = blockIdx.x * 256 + tid;
    const int x = p % W;
    const int y = p / W;
    const float fx = (float)(x * 4 + 2);
    const float fy = (float)(y * 4 + 2);

    float f[8];
#pragma unroll
    for (int o = 0; o < 8; ++o) f[o] = mf[o * HW + p];

#pragma unroll 2
    for (int j = 0; j < 10; ++j) {
        const float* spj = &sp[j * 169];
        const float rel0 = (float)(sdet[2 * j] * 4) - fx;
        const float rel1 = (float)(sdet[2 * j + 1] * 4) - fy;
        float h0[8];
#pragma unroll
        for (int o = 0; o < 8; ++o) {
            float a = spj[152 + o] + spj[o * 10] * rel0 + spj[o * 10 + 1] * rel1;
#pragma unroll
            for (int c = 0; c < 8; ++c) a += spj[o * 10 + 2 + c] * f[c];
            h0[o] = fmaxf(a, 0.f);
        }
        float h1[8];
#pragma unroll
        for (int o = 0; o < 8; ++o) {
            float a = spj[160 + o];
#pragma unroll
            for (int c = 0; c < 8; ++c) a += spj[80 + o * 8 + c] * h0[c];
            h1[o] = fmaxf(a, 0.f);
        }
        float r = spj[168];
#pragma unroll
        for (int c = 0; c < 8; ++c) r += spj[144 + c] * h1[c];
        out[(kg * 10 + j) * HW + p] = r;
    }
}

// ===========================================================================
extern "C" void kernel_launch(void* const* d_in, const int* in_sizes, int n_in,
                              void* d_out, int out_size, void* d_ws, size_t ws_size,
                              hipStream_t stream)
{
    const float* cnn    = (const float*)d_in[0];
    const float* towerw = (const float*)d_in[1];
    const float* gamma  = (const float*)d_in[2];
    const float* beta   = (const float*)d_in[3];
    const float* meanp  = (const float*)d_in[4];
    const float* varp   = (const float*)d_in[5];
    const float* projw  = (const float*)d_in[6];
    const float* projb  = (const float*)d_in[7];
    const float* ctrlw  = (const float*)d_in[8];
    const float* ctrlb  = (const float*)d_in[9];
    const int*   det    = (const int*)d_in[10];
    float* out = (float*)d_out;

    char*  outb     = (char*)d_out;
    char*  X        = outb;                          // 6,553,600 B
    char*  wbf      = outb + 6553600;                // 1,179,648 B
    float* invshift = (float*)(outb + 7733248);      // 4,096 B

    char*  Y      = (char*)d_ws;                     // 6,553,600 B
    float* mf     = (float*)((char*)d_ws + 6553600); // 819,200 B
    float* params = (float*)((char*)d_ws + 7372800); // 67,600 B

    const dim3 blk(256);

    prep_weights<<<dim3(256), blk, 0, stream>>>(towerw, gamma, beta, meanp, varp,
                                                wbf, invshift);
    prep_input<<<dim3(1600), blk, 0, stream>>>(cnn, X);

    const dim3 cgrid(10, 40);
    conv_mfma<0><<<cgrid, blk, 0, stream>>>(X, wbf + 0 * 294912, invshift + 0 * 256,
                                            Y, nullptr, nullptr, nullptr);
    conv_mfma<0><<<cgrid, blk, 0, stream>>>(Y, wbf + 1 * 294912, invshift + 1 * 256,
                                            X, nullptr, nullptr, nullptr);
    conv_mfma<0><<<cgrid, blk, 0, stream>>>(X, wbf + 2 * 294912, invshift + 2 * 256,
                                            Y, nullptr, nullptr, nullptr);
    conv_mfma<1><<<cgrid, blk, 0, stream>>>(Y, wbf + 3 * 294912, invshift + 3 * 256,
                                            nullptr, projw, projb, mf);

    ctrl_kernel<<<dim3(100), blk, 0, stream>>>(cnn, ctrlw, ctrlb, det, params);
    head_kernel<<<dim3(100, 10), blk, 0, stream>>>(mf, params, det, out);
}